// Round 5
// baseline (679.884 us; speedup 1.0000x reference)
//
#include <hip/hip_runtime.h>

// ExponentialUnitNorm: s_t = 0.01*|x_t| + 0.99*s_{t-1};  out_t = x_t / sqrt(s_t)
// x: [B=16, C=2, T=1000, F=481, 2] fp32.  init_state: [1,1,F,1] fp32.
//
// Single-kernel chained scan (cooperative launch -> co-residency -> spin-safe):
//   block (bc,c): stream chunk -> C_local (zero-init prefix);
//                 receive state[bc][c-1] (spin on flag, device-scope);
//                 publish s_out = aL*s_in + C_local (1 fma -> fast chain);
//                 re-read chunk (L2/L3-warm) and apply, write out.
// Grid = 32 chains x 16 chunks = 512 blocks x 512 thr = 2 blocks/CU
// (forced by __launch_bounds__(512,4) -> <=128 VGPR, co-residency guaranteed).
// Chunk lengths: 63 for c<8, else 62 (sum=1000).
// Flags live in ws, reset each call by in-graph hipMemsetAsync (2KB).

#define EPS_F 1e-14f

constexpr int B = 16, C = 2, T = 1000, F = 481;
constexpr int BC = B * C;            // 32
constexpr int NCHUNK = 16;
constexpr int NBLK = BC * NCHUNK;    // 512
constexpr int ROWS = F * 2;          // floats per t-row = 962

__device__ __forceinline__ int chunk_base(int c) { return c * 62 + (c < 8 ? c : 8); }
__device__ __forceinline__ int chunk_len(int c)  { return 62 + (c < 8 ? 1 : 0); }

__global__ __launch_bounds__(512, 4)
void k_chain(const float* __restrict__ x, const float* __restrict__ init_state,
             float* __restrict__ out, float* __restrict__ state,
             int* __restrict__ flags) {
    const int f  = threadIdx.x;
    const int c  = blockIdx.x % NCHUNK;
    const int bc = blockIdx.x / NCHUNK;
    const bool act = (f < F);
    const int t0 = chunk_base(c);
    const int L  = chunk_len(c);

    const float* xp = x + ((size_t)(bc * T + t0) * F + f) * 2;

    // phase 1: zero-init local prefix over own chunk (streams x into caches)
    float Cl = 0.0f;
    if (act) {
        for (int t = 0; t < L; ++t) {
            float2 v = *(const float2*)(xp + (size_t)t * ROWS);
            float m = fmaxf(fmaf(v.x, v.x, v.y * v.y), EPS_F);
            Cl = fmaf(0.99f, Cl, 0.01f * __builtin_amdgcn_sqrtf(m));
        }
    }
    // aL = 0.99^L (cheap, once per block)
    double p = 1.0;
    for (int i = 0; i < L; ++i) p *= 0.99;
    const float aL = (float)p;

    // phase 2: receive predecessor state
    float s0;
    if (c == 0) {
        s0 = act ? init_state[f] : 1.0f;
    } else {
        const int fi = bc * NCHUNK + (c - 1);
        if (threadIdx.x == 0) {
            while (__hip_atomic_load(&flags[fi], __ATOMIC_ACQUIRE,
                                     __HIP_MEMORY_SCOPE_AGENT) == 0)
                __builtin_amdgcn_s_sleep(8);
        }
        __syncthreads();
        s0 = act ? __hip_atomic_load(&state[(size_t)fi * F + f], __ATOMIC_RELAXED,
                                     __HIP_MEMORY_SCOPE_AGENT)
                 : 1.0f;
    }

    // phase 3: publish own outgoing state ASAP (before apply)
    if (c < NCHUNK - 1) {
        const int oi = bc * NCHUNK + c;
        if (act)
            __hip_atomic_store(&state[(size_t)oi * F + f], fmaf(aL, s0, Cl),
                               __ATOMIC_RELAXED, __HIP_MEMORY_SCOPE_AGENT);
        __threadfence();
        __syncthreads();
        if (threadIdx.x == 0)
            __hip_atomic_store(&flags[oi], 1, __ATOMIC_RELEASE,
                               __HIP_MEMORY_SCOPE_AGENT);
    }

    // phase 4: apply (re-read chunk, cache-warm) and write out
    if (act) {
        float s = s0;
        float* op = out + ((size_t)(bc * T + t0) * F + f) * 2;
        for (int t = 0; t < L; ++t) {
            float2 v = *(const float2*)(xp + (size_t)t * ROWS);
            float m = fmaxf(fmaf(v.x, v.x, v.y * v.y), EPS_F);
            s = fmaf(0.99f, s, 0.01f * __builtin_amdgcn_sqrtf(m));
            const float inv = __builtin_amdgcn_rsqf(s);
            float2 o;
            o.x = v.x * inv;
            o.y = v.y * inv;
            *(float2*)(op + (size_t)t * ROWS) = o;
        }
    }
}

extern "C" void kernel_launch(void* const* d_in, const int* in_sizes, int n_in,
                              void* d_out, int out_size, void* d_ws, size_t ws_size,
                              hipStream_t stream) {
    const float* x          = (const float*)d_in[0];
    const float* init_state = (const float*)d_in[1];
    float* out = (float*)d_out;

    float* state = (float*)d_ws;                       // NBLK * F floats
    int*   flags = (int*)(state + (size_t)NBLK * F);   // NBLK ints

    hipMemsetAsync(flags, 0, NBLK * sizeof(int), stream);

    void* args[] = {(void*)&x, (void*)&init_state, (void*)&out,
                    (void*)&state, (void*)&flags};
    hipLaunchCooperativeKernel((void*)k_chain, dim3(NBLK), dim3(512),
                               args, 0, stream);
}

// Round 6
// 101.151 us; speedup vs baseline: 6.7215x; 6.7215x over previous
//
#include <hip/hip_runtime.h>

// ExponentialUnitNorm: s_t = 0.01*|x_t| + 0.99*s_{t-1};  out_t = x_t / sqrt(s_t)
// x: [B=16, C=2, T=1000, F=481, 2] fp32.  init_state: [1,1,F,1] fp32.
//
// Fused single-kernel chained scan (cooperative launch, co-resident grid).
// R4 failed (679us) because the spin used ACQUIRE per poll -> per-XCD L2
// invalidate storm (CDNA4 L2s not cross-coherent; acquire at agent scope
// invalidates L2) and RELEASE flag stores -> buffer_wbl2 writeback storms.
// R5: ALL cross-block traffic via RELAXED agent-scope atomics (bypass L2 to
// the coherence point -> no invalidates, no writebacks). Hand-rolled release:
// relaxed state stores -> s_waitcnt vmcnt(0) (per wave) -> syncthreads ->
// lane0 relaxed flag store. Consumer: lane0 relaxed-polls, syncthreads,
// relaxed atomic state loads (coherence point already has released data).
//
// Grid = 32 chains x 16 chunks = 512 blocks x 512 thr (2 blocks/CU).
// Chunk lengths: 63 for c<8, else 62 (sum=1000). Flags zeroed in-graph.

#define EPS_F 1e-14f

constexpr int B = 16, C = 2, T = 1000, F = 481;
constexpr int BC = B * C;            // 32
constexpr int NCHUNK = 16;
constexpr int NBLK = BC * NCHUNK;    // 512
constexpr int ROWS = F * 2;          // floats per t-row = 962

__device__ __forceinline__ int chunk_base(int c) { return c * 62 + (c < 8 ? c : 8); }
__device__ __forceinline__ int chunk_len(int c)  { return 62 + (c < 8 ? 1 : 0); }

__global__ __launch_bounds__(512, 4)
void k_chain(const float* __restrict__ x, const float* __restrict__ init_state,
             float* __restrict__ out, float* __restrict__ state,
             int* __restrict__ flags) {
    const int f  = threadIdx.x;
    const int c  = blockIdx.x % NCHUNK;
    const int bc = blockIdx.x / NCHUNK;
    const bool act = (f < F);
    const int t0 = chunk_base(c);
    const int L  = chunk_len(c);

    const float* xp = x + ((size_t)(bc * T + t0) * F + f) * 2;

    // phase 1: zero-init local prefix over own chunk (streams x into caches)
    float Cl = 0.0f;
    if (act) {
        for (int t = 0; t < L; ++t) {
            float2 v = *(const float2*)(xp + (size_t)t * ROWS);
            float m = fmaxf(fmaf(v.x, v.x, v.y * v.y), EPS_F);
            Cl = fmaf(0.99f, Cl, 0.01f * __builtin_amdgcn_sqrtf(m));
        }
    }
    // aL = 0.99^L
    double p = 1.0;
    for (int i = 0; i < L; ++i) p *= 0.99;
    const float aL = (float)p;

    // phase 2: receive predecessor state (RELAXED poll — no L2 invalidates)
    float s0;
    if (c == 0) {
        s0 = act ? init_state[f] : 1.0f;
    } else {
        const int fi = bc * NCHUNK + (c - 1);
        if (threadIdx.x == 0) {
            while (__hip_atomic_load(&flags[fi], __ATOMIC_RELAXED,
                                     __HIP_MEMORY_SCOPE_AGENT) == 0)
                __builtin_amdgcn_s_sleep(2);
        }
        __syncthreads();
        s0 = act ? __hip_atomic_load(&state[(size_t)fi * F + f], __ATOMIC_RELAXED,
                                     __HIP_MEMORY_SCOPE_AGENT)
                 : 1.0f;
    }

    // phase 3: publish outgoing state ASAP (hand-rolled release, no wbl2)
    if (c < NCHUNK - 1) {
        const int oi = bc * NCHUNK + c;
        if (act)
            __hip_atomic_store(&state[(size_t)oi * F + f], fmaf(aL, s0, Cl),
                               __ATOMIC_RELAXED, __HIP_MEMORY_SCOPE_AGENT);
        asm volatile("s_waitcnt vmcnt(0)" ::: "memory");  // own wave's stores done
        __syncthreads();                                  // all waves joined
        if (threadIdx.x == 0)
            __hip_atomic_store(&flags[oi], 1, __ATOMIC_RELAXED,
                               __HIP_MEMORY_SCOPE_AGENT);
    }

    // phase 4: apply (re-read chunk, on-chip-warm) and write out
    if (act) {
        float s = s0;
        float* op = out + ((size_t)(bc * T + t0) * F + f) * 2;
        for (int t = 0; t < L; ++t) {
            float2 v = *(const float2*)(xp + (size_t)t * ROWS);
            float m = fmaxf(fmaf(v.x, v.x, v.y * v.y), EPS_F);
            s = fmaf(0.99f, s, 0.01f * __builtin_amdgcn_sqrtf(m));
            const float inv = __builtin_amdgcn_rsqf(s);
            float2 o;
            o.x = v.x * inv;
            o.y = v.y * inv;
            *(float2*)(op + (size_t)t * ROWS) = o;
        }
    }
}

extern "C" void kernel_launch(void* const* d_in, const int* in_sizes, int n_in,
                              void* d_out, int out_size, void* d_ws, size_t ws_size,
                              hipStream_t stream) {
    const float* x          = (const float*)d_in[0];
    const float* init_state = (const float*)d_in[1];
    float* out = (float*)d_out;

    float* state = (float*)d_ws;                       // NBLK * F floats
    int*   flags = (int*)(state + (size_t)NBLK * F);   // NBLK ints

    hipMemsetAsync(flags, 0, NBLK * sizeof(int), stream);

    void* args[] = {(void*)&x, (void*)&init_state, (void*)&out,
                    (void*)&state, (void*)&flags};
    hipLaunchCooperativeKernel((void*)k_chain, dim3(NBLK), dim3(512),
                               args, 0, stream);
}

// Round 7
// 83.314 us; speedup vs baseline: 8.1606x; 1.2141x over previous
//
#include <hip/hip_runtime.h>

// ExponentialUnitNorm: s_t = 0.01*|x_t| + 0.99*s_{t-1};  out_t = x_t / sqrt(s_t)
// x: [B=16, C=2, T=1000, F=481, 2] fp32.  init_state: [1,1,F,1] fp32.
//
// R6: ZERO-sync single-pass scan. One thread owns one (bc,f) chain and runs
// the exact sequential recurrence (reference algorithm, no chunk algebra).
// 15392 chains -> 241 blocks x 64 threads = ~1 wave per CU (64-thr blocks
// spread waves across CUs; 256-thr blocks would use only 61 CUs).
// Single-wave BW: need ~18 loads in flight (10 B/cy x ~900 cy HBM latency);
// manual depth-2 software pipeline with G=20-row groups keeps up to 20
// wave-loads (10 KB) outstanding. All buffer indices are compile-time static
// (runtime-indexed arrays would spill to scratch). Loads are independent of
// the serial s-chain (1 FMA/row), so issue is never gated by compute.
// Traffic: x read ONCE (123 MB) + out written once (123 MB). No atomics,
// no barriers, no workspace.

#define EPS_F 1e-14f

constexpr int B = 16, C = 2, T = 1000, F = 481;
constexpr int BC = B * C;          // 32
constexpr int NCHAIN = BC * F;     // 15392
constexpr int ROWS = F * 2;        // floats per t-row = 962
constexpr int G = 20;              // rows per pipeline group
constexpr int NG = T / G;          // 50 groups (exact)

__global__ __launch_bounds__(64)
void k_scan(const float* __restrict__ x, const float* __restrict__ init_state,
            float* __restrict__ out) {
    const int g = blockIdx.x * 64 + threadIdx.x;
    if (g >= NCHAIN) return;
    const int bc = g / F;
    const int f  = g - bc * F;
    const size_t base = ((size_t)bc * T * F + f) * 2;
    const float* xp = x + base;
    float* op = out + base;

    float s = init_state[f];
    float2 bufA[G], bufB[G];

    // preload group 0
#pragma unroll
    for (int j = 0; j < G; ++j)
        bufA[j] = *(const float2*)(xp + (size_t)j * ROWS);

    // process groups in pairs: even group from bufA, odd from bufB
    for (int p = 0; p < NG / 2; ++p) {
        const float* xA = xp + (size_t)(2 * p) * G * ROWS;
        const float* xB = xA + (size_t)G * ROWS;
        float* oA = op + (size_t)(2 * p) * G * ROWS;
        float* oB = oA + (size_t)G * ROWS;

        // issue loads for group 2p+1 (independent of compute below)
#pragma unroll
        for (int j = 0; j < G; ++j)
            bufB[j] = *(const float2*)(xB + (size_t)j * ROWS);

        // compute + store group 2p from bufA
#pragma unroll
        for (int j = 0; j < G; ++j) {
            float2 v = bufA[j];
            float m = fmaxf(fmaf(v.x, v.x, v.y * v.y), EPS_F);
            s = fmaf(0.99f, s, 0.01f * __builtin_amdgcn_sqrtf(m));
            const float inv = __builtin_amdgcn_rsqf(s);
            float2 o;
            o.x = v.x * inv;
            o.y = v.y * inv;
            *(float2*)(oA + (size_t)j * ROWS) = o;
        }

        // issue loads for group 2p+2
        if (p < NG / 2 - 1) {
            const float* xC = xB + (size_t)G * ROWS;
#pragma unroll
            for (int j = 0; j < G; ++j)
                bufA[j] = *(const float2*)(xC + (size_t)j * ROWS);
        }

        // compute + store group 2p+1 from bufB
#pragma unroll
        for (int j = 0; j < G; ++j) {
            float2 v = bufB[j];
            float m = fmaxf(fmaf(v.x, v.x, v.y * v.y), EPS_F);
            s = fmaf(0.99f, s, 0.01f * __builtin_amdgcn_sqrtf(m));
            const float inv = __builtin_amdgcn_rsqf(s);
            float2 o;
            o.x = v.x * inv;
            o.y = v.y * inv;
            *(float2*)(oB + (size_t)j * ROWS) = o;
        }
    }
}

extern "C" void kernel_launch(void* const* d_in, const int* in_sizes, int n_in,
                              void* d_out, int out_size, void* d_ws, size_t ws_size,
                              hipStream_t stream) {
    const float* x          = (const float*)d_in[0];
    const float* init_state = (const float*)d_in[1];
    float* out = (float*)d_out;

    k_scan<<<dim3((NCHAIN + 63) / 64), 64, 0, stream>>>(x, init_state, out);
}

// Round 8
// 68.151 us; speedup vs baseline: 9.9761x; 1.2225x over previous
//
#include <hip/hip_runtime.h>

// ExponentialUnitNorm: s_t = 0.01*|x_t| + 0.99*s_{t-1};  out_t = x_t / sqrt(s_t)
// x: [B=16, C=2, T=1000, F=481, 2] fp32.  init_state: [1,1,F,1] fp32.
//
// R7 = R2 (best, 65.7us) + ONE change: non-temporal stores for `out`.
// Theory: out's 123MB write stream allocates in the 256MB Infinity Cache and
// evicts x (123MB) between replays (evidence: R6 FETCH=75MB — partial x
// survival). nt-stores keep L3 = {x, csum} -> both passes' x reads are
// L3 hits at steady state; HBM carries only the write-through out stream.
//
//   pass1 (k_chunksum): per (bc, chunk, f) zero-init partial sum C_k
//   pass2 (k_apply):    prefix over csum (L2-hot), rerun chunk, nt-write out.

#define ALPHA_F 0.99f
#define OMA_F   0.01f
#define EPS_F   1e-14f

constexpr int B = 16, C = 2, T = 1000, F = 481;
constexpr int BC = B * C;          // 32
constexpr int NCHUNK = 20;
constexpr int L = T / NCHUNK;      // 50
constexpr int ROWS = F * 2;        // floats per t-row = 962

__global__ __launch_bounds__(512)
void k_chunksum(const float* __restrict__ x, float* __restrict__ csum) {
    const int f = threadIdx.x;
    const int chunk = blockIdx.x % NCHUNK;
    const int bc = blockIdx.x / NCHUNK;
    if (f >= F) return;
    const float* xp = x + ((size_t)(bc * T + chunk * L) * F + f) * 2;
    float s = 0.0f;
#pragma unroll 5
    for (int t = 0; t < L; ++t) {
        float2 v = *(const float2*)(xp + (size_t)t * ROWS);
        float m = fmaxf(fmaf(v.x, v.x, v.y * v.y), EPS_F);
        float xa = __builtin_amdgcn_sqrtf(m);
        s = fmaf(ALPHA_F, s, OMA_F * xa);
    }
    csum[(bc * NCHUNK + chunk) * F + f] = s;
}

__global__ __launch_bounds__(512)
void k_apply(const float* __restrict__ x,
             const float* __restrict__ csum,
             const float* __restrict__ init_state,
             float* __restrict__ out) {
    const int f = threadIdx.x;
    const int chunk = blockIdx.x % NCHUNK;
    const int bc = blockIdx.x / NCHUNK;
    if (f >= F) return;

    // a^L (compiler-folded)
    double aLd = 1.0;
    for (int i = 0; i < L; ++i) aLd *= 0.99;
    const float aL = (float)aLd;

    // chunk-init: prefix over csum for k < chunk (L2-hot, coalesced)
    float s = init_state[f];
    for (int k = 0; k < chunk; ++k)
        s = fmaf(aL, s, csum[(bc * NCHUNK + k) * F + f]);

    const size_t base = ((size_t)(bc * T + chunk * L) * F + f) * 2;
    const float* xp = x + base;
    float* op = out + base;
#pragma unroll 5
    for (int t = 0; t < L; ++t) {
        float2 v = *(const float2*)(xp + (size_t)t * ROWS);
        float m = fmaxf(fmaf(v.x, v.x, v.y * v.y), EPS_F);
        float xa = __builtin_amdgcn_sqrtf(m);
        s = fmaf(ALPHA_F, s, OMA_F * xa);
        const float inv = __builtin_amdgcn_rsqf(s);
        float2 o;
        o.x = v.x * inv;
        o.y = v.y * inv;
        union { float2 f2; unsigned long long u; } cv;
        cv.f2 = o;
        __builtin_nontemporal_store(cv.u, (unsigned long long*)(op + (size_t)t * ROWS));
    }
}

extern "C" void kernel_launch(void* const* d_in, const int* in_sizes, int n_in,
                              void* d_out, int out_size, void* d_ws, size_t ws_size,
                              hipStream_t stream) {
    const float* x          = (const float*)d_in[0];
    const float* init_state = (const float*)d_in[1];
    float* out = (float*)d_out;

    float* csum = (float*)d_ws;  // BC*NCHUNK*F floats = 1.23 MB

    k_chunksum<<<dim3(BC * NCHUNK), 512, 0, stream>>>(x, csum);
    k_apply<<<dim3(BC * NCHUNK), 512, 0, stream>>>(x, csum, init_state, out);
}

// Round 11
// 45.364 us; speedup vs baseline: 14.9874x; 1.5023x over previous
//
#include <hip/hip_runtime.h>

// ExponentialUnitNorm: s_t = 0.01*|x_t| + 0.99*s_{t-1};  out_t = x_t / sqrt(s_t)
// x: [B=16, C=2, T=1000, F=481, 2] fp32.  init_state: [1,1,F,1] fp32.
//
// R10: single-kernel register-stash scan with INTRA-BLOCK sync only.
// (R8/R9 post-mortem: absmax == empty-stub value -> cooperative launch was
// REJECTED (co-residency check vs ~128-VGPR kernel), kernels never ran.)
// Block = (bc, 64-wide f-tile), 512 thr = 8 waves. T=1000 in 5 super-steps
// of 200 rows; wave w owns rows [s*200+w*25, +25). Per step:
//   stash 25 float2 rows in regs; zero-init partial sum Cl (L=25 chunk
//   algebra, verified R3); lds_c[w][fx]=Cl; syncthreads;
//   chunk-init = carry[fx] composed with lds_c[0..w-1] (<=7 fmas);
//   syncthreads; wave7 writes next carry; apply from regs, write out.
// x read ONCE (123MB), out written once (123MB). No atomics, no cooperative
// launch, no workspace. Grid 256 blocks x 512 thr ~= 1 block/CU.

#define EPS_F 1e-14f

constexpr int B = 16, C = 2, T = 1000, F = 481;
constexpr int BC = B * C;        // 32
constexpr int FW = 64;           // f-tile width = one wave
constexpr int NTILE = 8;         // ceil(481/64)
constexpr int WV = 8;            // waves per block
constexpr int RW = 25;           // rows per wave-chunk
constexpr int RSTEP = WV * RW;   // 200
constexpr int NSUP = T / RSTEP;  // 5 (exact)
constexpr int ROWS = F * 2;      // 962 floats per t-row

__global__ __launch_bounds__(512, 4)
void k_fused(const float* __restrict__ x, const float* __restrict__ init_state,
             float* __restrict__ out) {
    __shared__ float lds_c[WV][FW];
    __shared__ float carry[FW];

    const int fx   = threadIdx.x & (FW - 1);
    const int w    = threadIdx.x >> 6;
    const int bc   = blockIdx.x & (BC - 1);
    const int tile = blockIdx.x >> 5;
    const int f    = tile * FW + fx;
    const bool act = (f < F);

    double p = 1.0;
    for (int i = 0; i < RW; ++i) p *= 0.99;
    const float A25 = (float)p;

    if (threadIdx.x < FW) carry[fx] = act ? init_state[f] : 1.0f;
    // first read of carry is after step-0's syncthreads -> visible.

    for (int s = 0; s < NSUP; ++s) {
        const int t0 = s * RSTEP + w * RW;
        const float* xp = x + ((size_t)(bc * T + t0) * F + f) * 2;

        // stash 25 rows in registers (25 independent coalesced loads)
        float2 v[RW];
#pragma unroll
        for (int j = 0; j < RW; ++j)
            if (act) v[j] = *(const float2*)(xp + (size_t)j * ROWS);

        // zero-init partial sum over own wave-chunk
        float Cl = 0.0f;
#pragma unroll
        for (int j = 0; j < RW; ++j)
            if (act) {
                float m = fmaxf(fmaf(v[j].x, v[j].x, v[j].y * v[j].y), EPS_F);
                Cl = fmaf(0.99f, Cl, 0.01f * __builtin_amdgcn_sqrtf(m));
            }
        lds_c[w][fx] = Cl;
        __syncthreads();  // A: lds_c ready (also orders prev-step carry write)

        // chunk-init: carry + prefix of earlier waves' partials
        float sloc = carry[fx];
#pragma unroll
        for (int jw = 0; jw < WV - 1; ++jw)
            if (jw < w) sloc = fmaf(A25, sloc, lds_c[jw][fx]);
        __syncthreads();  // B: all carry/lds_c reads done

        if (w == WV - 1) carry[fx] = fmaf(A25, sloc, Cl);  // next step's carry

        // apply from registers, write out
        float* op = out + ((size_t)(bc * T + t0) * F + f) * 2;
#pragma unroll
        for (int j = 0; j < RW; ++j)
            if (act) {
                float m = fmaxf(fmaf(v[j].x, v[j].x, v[j].y * v[j].y), EPS_F);
                sloc = fmaf(0.99f, sloc, 0.01f * __builtin_amdgcn_sqrtf(m));
                const float inv = __builtin_amdgcn_rsqf(sloc);
                float2 o;
                o.x = v[j].x * inv;
                o.y = v[j].y * inv;
                *(float2*)(op + (size_t)j * ROWS) = o;
            }
    }
}

extern "C" void kernel_launch(void* const* d_in, const int* in_sizes, int n_in,
                              void* d_out, int out_size, void* d_ws, size_t ws_size,
                              hipStream_t stream) {
    const float* x          = (const float*)d_in[0];
    const float* init_state = (const float*)d_in[1];
    float* out = (float*)d_out;

    k_fused<<<dim3(NTILE * BC), 512, 0, stream>>>(x, init_state, out);
}